// Round 7
// baseline (398.685 us; speedup 1.0000x reference)
//
#include <hip/hip_runtime.h>

#define S_LEN 1024
#define HID   768
#define T_SZ  9
#define NEG_VAL (-1e12f)

typedef __bf16 bf16x8 __attribute__((ext_vector_type(8)));
typedef float  f32x4  __attribute__((ext_vector_type(4)));
typedef short  short8 __attribute__((ext_vector_type(8)));
typedef short  short4v __attribute__((ext_vector_type(4)));
typedef float  float4v __attribute__((ext_vector_type(4)));

__device__ __forceinline__ unsigned short f2bf(float f) {
    unsigned int u = __builtin_bit_cast(unsigned int, f);
    u += 0x7FFFu + ((u >> 16) & 1u);          // RNE
    return (unsigned short)(u >> 16);
}

__device__ __forceinline__ short8 pack8(float4v a, float4v b) {
    short8 o;
    o[0] = (short)f2bf(a[0]); o[1] = (short)f2bf(a[1]);
    o[2] = (short)f2bf(a[2]); o[3] = (short)f2bf(a[3]);
    o[4] = (short)f2bf(b[0]); o[5] = (short)f2bf(b[1]);
    o[6] = (short)f2bf(b[2]); o[7] = (short)f2bf(b[3]);
    return o;
}

// async global->LDS, 16B per lane, linear dest (wave-uniform base + lane*16)
__device__ __forceinline__ void gload_lds16(const void* g, void* l) {
    __builtin_amdgcn_global_load_lds(
        (const __attribute__((address_space(1))) unsigned int*)g,
        (__attribute__((address_space(3))) unsigned int*)l,
        16, 0, 0);
}

// ---------------- kernel 1: fused convert + proj GEMM (dbuf, 1 barrier/K-step) + RoPE ----------------
union __align__(16) SmP {
    unsigned short buf[2][2][128 * 64];   // [parity][A=0/B=1] bf16, 64 KB
    unsigned short Tr[128 * 136];         // col-major C bounce, 34.8 KB
};

__global__ __launch_bounds__(256) void k_proj(
    const float* __restrict__ hidden,   // [B*S][768] fp32
    const float* __restrict__ W,        // [1152][768] fp32
    const float* __restrict__ bias,
    unsigned short* __restrict__ qout,
    unsigned short* __restrict__ kout)
{
    __shared__ SmP sm;
    int tid = threadIdx.x;
    int blk = blockIdx.x;
    int mt = blk / T_SZ;
    int t  = blk % T_SZ;
    int m0 = mt * 128;
    int n0 = t * 128;

    int lane = tid & 63;
    int wave = tid >> 6;
    int lr = lane & 15;
    int lq = lane >> 4;
    int wrow = wave * 32;

    float bv[8];
    #pragma unroll
    for (int fn = 0; fn < 8; ++fn) bv[fn] = bias[n0 + fn * 16 + lr];

    // per-lane pre-swizzled fp32 sources; LDS slot gsi holds data seg = slot ^ (r&7)
    const float* aP[4];
    const float* bP[4];
    #pragma unroll
    for (int it = 0; it < 4; ++it) {
        int gsi = (wave * 4 + it) * 64 + lane;
        int r = gsi >> 3;
        int sw = gsi & 7;
        int seg8 = (sw ^ (r & 7)) << 3;
        aP[it] = hidden + (size_t)(m0 + r) * HID + seg8;
        bP[it] = W      + (size_t)(n0 + r) * HID + seg8;
    }

    f32x4 acc[2][8];
    #pragma unroll
    for (int i = 0; i < 2; ++i)
        #pragma unroll
        for (int j = 0; j < 8; ++j) acc[i][j] = (f32x4){0.f, 0.f, 0.f, 0.f};

    // reg staging (T14): loads for step kk issued at end of step kk-1
    float4v ar[4][2], br[4][2];
    #pragma unroll
    for (int it = 0; it < 4; ++it) {
        ar[it][0] = *(const float4v*)(aP[it]);
        ar[it][1] = *(const float4v*)(aP[it] + 4);
        br[it][0] = *(const float4v*)(bP[it]);
        br[it][1] = *(const float4v*)(bP[it] + 4);
    }

    for (int kk = 0; kk < HID / 64; ++kk) {
        int par = kk & 1;
        #pragma unroll
        for (int it = 0; it < 4; ++it) {
            int slot = ((wave * 4 + it) * 64 + lane) * 8;
            *(short8*)&sm.buf[par][0][slot] = pack8(ar[it][0], ar[it][1]);
            *(short8*)&sm.buf[par][1][slot] = pack8(br[it][0], br[it][1]);
        }
        if (kk < HID / 64 - 1) {
            #pragma unroll
            for (int it = 0; it < 4; ++it) {
                ar[it][0] = *(const float4v*)(aP[it] + (kk + 1) * 64);
                ar[it][1] = *(const float4v*)(aP[it] + (kk + 1) * 64 + 4);
                br[it][0] = *(const float4v*)(bP[it] + (kk + 1) * 64);
                br[it][1] = *(const float4v*)(bP[it] + (kk + 1) * 64 + 4);
            }
        }
        __syncthreads();   // buf[par] writes visible; prior readers of buf[par] long done
        #pragma unroll
        for (int kb = 0; kb < 2; ++kb) {
            bf16x8 af[2];
            #pragma unroll
            for (int fm = 0; fm < 2; ++fm) {
                int r = wrow + fm * 16 + lr;
                int seg = kb * 4 + lq;
                af[fm] = *(const bf16x8*)&sm.buf[par][0][r * 64 + ((seg ^ (r & 7)) * 8)];
            }
            #pragma unroll
            for (int fn = 0; fn < 8; ++fn) {
                int r = fn * 16 + lr;
                int seg = kb * 4 + lq;
                bf16x8 bfr = *(const bf16x8*)&sm.buf[par][1][r * 64 + ((seg ^ (r & 7)) * 8)];
                acc[0][fn] = __builtin_amdgcn_mfma_f32_16x16x32_bf16(af[0], bfr, acc[0][fn], 0, 0, 0);
                acc[1][fn] = __builtin_amdgcn_mfma_f32_16x16x32_bf16(af[1], bfr, acc[1][fn], 0, 0, 0);
            }
        }
    }
    __syncthreads();   // all MFMA reads done before Tr aliases the bufs

    // bounce C (bias added) to col-major LDS bf16
    #pragma unroll
    for (int fm = 0; fm < 2; ++fm) {
        #pragma unroll
        for (int fn = 0; fn < 8; ++fn) {
            int col = fn * 16 + lr;
            int r0 = wrow + fm * 16 + lq * 4;
            short4v pk;
            #pragma unroll
            for (int j = 0; j < 4; ++j) pk[j] = (short)f2bf(acc[fm][fn][j] + bv[fn]);
            *(short4v*)&sm.Tr[col * 136 + r0] = pk;
        }
    }
    __syncthreads();

    // RoPE epilogue: thread owns dim d for 32 consecutive rows; cos/sin via rotation recurrence
    int d = tid & 63;
    int grp = tid >> 6;
    int cq = 2 * d, ck = 2 * d + 1;
    int pq = (d < 32) ? (4 * d + 2) : (4 * (d - 32));
    int pk2 = pq + 1;
    float sgn = (d < 32) ? -1.0f : 1.0f;

    float theta = exp2f(-13.2877123795f * (float)(d >> 1) * (1.0f / 32.0f));  // 10000^(-(d>>1)/32)
    int sBase = (m0 & (S_LEN - 1)) + grp * 32;    // block never crosses batch boundary
    int bb = m0 >> 10;
    float cv, sv, ct, st;
    __builtin_sincosf((float)sBase * theta, &sv, &cv);
    __builtin_sincosf(theta, &st, &ct);
    size_t obase = (((size_t)bb * T_SZ + t) * S_LEN + sBase) * 64 + d;

    #pragma unroll
    for (int ch = 0; ch < 4; ++ch) {
        int r0 = grp * 32 + ch * 8;
        bf16x8 xq = *(const bf16x8*)&sm.Tr[cq * 136 + r0];
        bf16x8 xk = *(const bf16x8*)&sm.Tr[ck * 136 + r0];
        bf16x8 yq = *(const bf16x8*)&sm.Tr[pq * 136 + r0];
        bf16x8 yk = *(const bf16x8*)&sm.Tr[pk2 * 136 + r0];
        #pragma unroll
        for (int rr = 0; rr < 8; ++rr) {
            float qv = (float)xq[rr] * cv + sgn * (float)yq[rr] * sv;
            float kv = (float)xk[rr] * cv + sgn * (float)yk[rr] * sv;
            size_t ob = obase + (size_t)(ch * 8 + rr) * 64;
            qout[ob] = f2bf(qv);
            kout[ob] = f2bf(kv);
            float c2 = cv * ct - sv * st;       // rotate angle by +theta
            sv = sv * ct + cv * st;
            cv = c2;
        }
    }
}

// ---------------- kernel 2: logits, 128x256 tiles, fill merged ----------------
__global__ __launch_bounds__(256) void k_logits(
    const unsigned short* __restrict__ q,
    const unsigned short* __restrict__ k,
    const int* __restrict__ mask,
    float* __restrict__ out)
{
    int tid = threadIdx.x;
    int blk = blockIdx.x;
    int bt  = blk >> 5;
    int rem = blk & 31;
    int ti  = rem >> 2;        // 0..7 (row tile, 128)
    int tj2 = rem & 3;         // 0..3 (col tile, 256)
    size_t obase = ((size_t)bt * S_LEN + (size_t)ti * 128) * S_LEN + (size_t)tj2 * 256;

    if (ti >= 2 * tj2 + 2) {   // strictly below diagonal: pure NEG fill
        float4v nv = {NEG_VAL, NEG_VAL, NEG_VAL, NEG_VAL};
        #pragma unroll
        for (int it = 0; it < 32; ++it) {
            int idx = it * 256 + tid;
            int r = idx >> 6;
            int c4 = idx & 63;
            __builtin_nontemporal_store(nv, (float4v*)&out[obase + (size_t)r * S_LEN + c4 * 4]);
        }
        return;
    }

    __shared__ __align__(16) unsigned short As[128 * 64];   // q tile
    __shared__ __align__(16) unsigned short Bs[256 * 64];   // k tile
    __shared__ int mi[128], mj[256];

    int b = bt / T_SZ;
    if (tid < 128) mi[tid] = mask[b * S_LEN + ti * 128 + tid];
    mj[tid] = mask[b * S_LEN + tj2 * 256 + tid];

    const unsigned short* qsrc = q + ((size_t)bt * S_LEN + (size_t)ti * 128) * 64;
    const unsigned short* ksrc = k + ((size_t)bt * S_LEN + (size_t)tj2 * 256) * 64;

    int lane = tid & 63;
    int wave = tid >> 6;
    #pragma unroll
    for (int it = 0; it < 4; ++it) {
        int gsi = (wave * 4 + it) * 64 + lane;
        int rr = gsi >> 3;
        int sw = gsi & 7;
        gload_lds16(qsrc + rr * 64 + ((sw ^ (rr & 7)) << 3), &As[(wave * 4 + it) * 512]);
    }
    #pragma unroll
    for (int it = 0; it < 8; ++it) {
        int gsi = (wave * 8 + it) * 64 + lane;
        int rr = gsi >> 3;
        int sw = gsi & 7;
        gload_lds16(ksrc + rr * 64 + ((sw ^ (rr & 7)) << 3), &Bs[(wave * 8 + it) * 512]);
    }
    __syncthreads();

    int lr = lane & 15;
    int lq = lane >> 4;
    int wrow = wave * 32;

    f32x4 acc[2][16];
    #pragma unroll
    for (int i = 0; i < 2; ++i)
        #pragma unroll
        for (int j = 0; j < 16; ++j) acc[i][j] = (f32x4){0.f, 0.f, 0.f, 0.f};

    // swapped operands: D = K.Q^T -> lane&15 = out ROW (q), reg idx = out COL (k)
    #pragma unroll
    for (int kb = 0; kb < 2; ++kb) {
        bf16x8 qf[2];
        #pragma unroll
        for (int fi = 0; fi < 2; ++fi) {
            int rr = wrow + fi * 16 + lr;
            int seg = kb * 4 + lq;
            qf[fi] = *(const bf16x8*)&As[rr * 64 + ((seg ^ (rr & 7)) * 8)];
        }
        #pragma unroll
        for (int fn = 0; fn < 16; ++fn) {
            int rr = fn * 16 + lr;
            int seg = kb * 4 + lq;
            bf16x8 kf = *(const bf16x8*)&Bs[rr * 64 + ((seg ^ (rr & 7)) * 8)];
            acc[0][fn] = __builtin_amdgcn_mfma_f32_16x16x32_bf16(kf, qf[0], acc[0][fn], 0, 0, 0);
            acc[1][fn] = __builtin_amdgcn_mfma_f32_16x16x32_bf16(kf, qf[1], acc[1][fn], 0, 0, 0);
        }
    }

    #pragma unroll
    for (int fi = 0; fi < 2; ++fi) {
        int il = wrow + fi * 16 + lr;
        int gi = ti * 128 + il;
        bool mrow = mi[il] != 0;
        size_t rbase = obase + (size_t)il * S_LEN;
        #pragma unroll
        for (int fn = 0; fn < 16; ++fn) {
            int j0 = fn * 16 + lq * 4;
            int gj0 = tj2 * 256 + j0;
            float4v v;
            #pragma unroll
            for (int e = 0; e < 4; ++e) {
                bool ok = mrow && (mj[j0 + e] != 0) && (gi <= gj0 + e);
                v[e] = ok ? acc[fi][fn][e] : NEG_VAL;
            }
            __builtin_nontemporal_store(v, (float4v*)&out[rbase + j0]);
        }
    }
}

extern "C" void kernel_launch(void* const* d_in, const int* in_sizes, int n_in,
                              void* d_out, int out_size, void* d_ws, size_t ws_size,
                              hipStream_t stream) {
    const float* hidden = (const float*)d_in[0];
    const int*   mask   = (const int*)d_in[1];
    const float* W      = (const float*)d_in[2];
    const float* bias   = (const float*)d_in[3];
    float* out = (float*)d_out;
    int Bsz = in_sizes[0] / (S_LEN * HID);

    unsigned short* qb = (unsigned short*)d_ws;
    size_t qkElems = (size_t)Bsz * T_SZ * S_LEN * 64;
    unsigned short* kb = qb + qkElems;

    int nproj = Bsz * 8 * T_SZ;           // 576
    int ntile = Bsz * T_SZ * 32;          // 2304 (20 compute + 12 fill per bt)

    k_proj<<<dim3(nproj), dim3(256), 0, stream>>>(hidden, W, bias, qb, kb);
    k_logits<<<dim3(ntile), dim3(256), 0, stream>>>(qb, kb, mask, out);
}

// Round 8
// 368.955 us; speedup vs baseline: 1.0806x; 1.0806x over previous
//
#include <hip/hip_runtime.h>

#define S_LEN 1024
#define HID   768
#define T_SZ  9
#define NEG_VAL (-1e12f)

typedef __bf16 bf16x8 __attribute__((ext_vector_type(8)));
typedef float  f32x4  __attribute__((ext_vector_type(4)));
typedef short  short8 __attribute__((ext_vector_type(8)));
typedef short  short4v __attribute__((ext_vector_type(4)));
typedef float  float4v __attribute__((ext_vector_type(4)));

__device__ __forceinline__ unsigned short f2bf(float f) {
    unsigned int u = __builtin_bit_cast(unsigned int, f);
    u += 0x7FFFu + ((u >> 16) & 1u);          // RNE
    return (unsigned short)(u >> 16);
}

// async global->LDS, 16B per lane, linear dest (wave-uniform base + lane*16)
__device__ __forceinline__ void gload_lds16(const void* g, void* l) {
    __builtin_amdgcn_global_load_lds(
        (const __attribute__((address_space(1))) unsigned int*)g,
        (__attribute__((address_space(3))) unsigned int*)l,
        16, 0, 0);
}

__device__ __forceinline__ void do_convert(const float* __restrict__ src,
                                           unsigned short* __restrict__ dst, int i) {
    float4v a = *((const float4v*)src + (size_t)i * 2);
    float4v b = *((const float4v*)src + (size_t)i * 2 + 1);
    short8 o;
    o[0] = (short)f2bf(a[0]); o[1] = (short)f2bf(a[1]);
    o[2] = (short)f2bf(a[2]); o[3] = (short)f2bf(a[3]);
    o[4] = (short)f2bf(b[0]); o[5] = (short)f2bf(b[1]);
    o[6] = (short)f2bf(b[2]); o[7] = (short)f2bf(b[3]);
    *(short8*)(dst + (size_t)i * 8) = o;
}

// ---------------- kernel 1: converts + rope tables, one launch ----------------
__global__ __launch_bounds__(256) void k_prep(
    const float* __restrict__ hidden, const float* __restrict__ W,
    unsigned short* __restrict__ hidB, unsigned short* __restrict__ wB,
    float* __restrict__ cosT, float* __restrict__ sinT, int n8h, int n8w)
{
    int i = blockIdx.x * 256 + threadIdx.x;
    if (i < n8h) { do_convert(hidden, hidB, i); return; }
    i -= n8h;
    if (i < n8w) { do_convert(W, wB, i); return; }
    i -= n8w;
    if (i < S_LEN * 64) {
        int s = i >> 6;
        int d = i & 63;
        float theta = exp2f(-13.2877123795f * (float)(d >> 1) * (1.0f / 32.0f)); // 10000^(-(d/2)/32)
        float ang = (float)s * theta;
        float sv, cv;
        sincosf(ang, &sv, &cv);
        cosT[i] = cv;
        sinT[i] = sv;
    }
}

// ---------------- kernel 2: proj GEMM (2-phase dbuf) + RoPE, fill tiles merged ----------------
union __align__(16) SmP {
    unsigned short buf[2][2][128 * 64];   // [parity][A=0/B=1][row*64 + swz]  = 64 KB
    unsigned short Tr[128 * 136];         // col-major C bounce, 34.8 KB
};

__global__ __launch_bounds__(256) void k_proj_fill(
    const unsigned short* __restrict__ hidB,   // [B*S][768] bf16
    const unsigned short* __restrict__ wB,     // [1152][768] bf16
    const float* __restrict__ bias,
    const float* __restrict__ cosT,
    const float* __restrict__ sinT,
    unsigned short* __restrict__ qout,
    unsigned short* __restrict__ kout,
    float* __restrict__ out, int nproj)
{
    __shared__ SmP sm;
    int tid = threadIdx.x;
    int blk = blockIdx.x;

    if (blk >= nproj) {
        // strictly-below-diagonal NEG fill, overlapped with proj compute
        int f = blk - nproj;
        int bt = f / 28, rr = f % 28;
        int ti = 1; while (rr >= ti) { rr -= ti; ++ti; }
        size_t obase = ((size_t)bt * S_LEN + (size_t)ti * 128) * S_LEN + rr * 128;
        float4v nv = {NEG_VAL, NEG_VAL, NEG_VAL, NEG_VAL};
        #pragma unroll
        for (int it = 0; it < 16; ++it) {
            int idx = it * 256 + tid;
            int r = idx >> 5;
            int c4 = idx & 31;
            *(float4v*)&out[obase + (size_t)r * S_LEN + c4 * 4] = nv;
        }
        return;
    }

    int mt = blk / T_SZ;
    int t  = blk % T_SZ;
    int m0 = mt * 128;
    int n0 = t * 128;

    int lane = tid & 63;
    int wave = tid >> 6;
    int lr = lane & 15;
    int lq = lane >> 4;
    int wrow = wave * 32;

    float bv[8];
    #pragma unroll
    for (int fn = 0; fn < 8; ++fn) bv[fn] = bias[n0 + fn * 16 + lr];

    // per-lane pre-swizzled staging sources: linear LDS slot gsi holds data seg = slot ^ (r&7)
    const unsigned short* aSrc[4];
    const unsigned short* bSrc[4];
    #pragma unroll
    for (int it = 0; it < 4; ++it) {
        int gsi = (wave * 4 + it) * 64 + lane;
        int r = gsi >> 3;
        int sw = gsi & 7;
        int seg8 = (sw ^ (r & 7)) << 3;
        aSrc[it] = hidB + (size_t)(m0 + r) * HID + seg8;
        bSrc[it] = wB  + (size_t)(n0 + r) * HID + seg8;
    }

    f32x4 acc[2][8];
    #pragma unroll
    for (int i = 0; i < 2; ++i)
        #pragma unroll
        for (int j = 0; j < 8; ++j) acc[i][j] = (f32x4){0.f, 0.f, 0.f, 0.f};

    // prologue stage
    #pragma unroll
    for (int it = 0; it < 4; ++it) {
        gload_lds16(aSrc[it], &sm.buf[0][0][(wave * 4 + it) * 512]);
        gload_lds16(bSrc[it], &sm.buf[0][1][(wave * 4 + it) * 512]);
    }
    __syncthreads();

    for (int kk = 0; kk < HID / 64; ++kk) {
        int par = kk & 1;
        if (kk < HID / 64 - 1) {       // issue next K-step's loads; latency hides under MFMA
            #pragma unroll
            for (int it = 0; it < 4; ++it) {
                gload_lds16(aSrc[it] + (kk + 1) * 64, &sm.buf[par ^ 1][0][(wave * 4 + it) * 512]);
                gload_lds16(bSrc[it] + (kk + 1) * 64, &sm.buf[par ^ 1][1][(wave * 4 + it) * 512]);
            }
        }
        #pragma unroll
        for (int kb = 0; kb < 2; ++kb) {
            bf16x8 af[2];
            #pragma unroll
            for (int fm = 0; fm < 2; ++fm) {
                int r = wrow + fm * 16 + lr;
                int seg = kb * 4 + lq;
                af[fm] = *(const bf16x8*)&sm.buf[par][0][r * 64 + ((seg ^ (r & 7)) * 8)];
            }
            #pragma unroll
            for (int fn = 0; fn < 8; ++fn) {
                int r = fn * 16 + lr;
                int seg = kb * 4 + lq;
                bf16x8 bfr = *(const bf16x8*)&sm.buf[par][1][r * 64 + ((seg ^ (r & 7)) * 8)];
                acc[0][fn] = __builtin_amdgcn_mfma_f32_16x16x32_bf16(af[0], bfr, acc[0][fn], 0, 0, 0);
                acc[1][fn] = __builtin_amdgcn_mfma_f32_16x16x32_bf16(af[1], bfr, acc[1][fn], 0, 0, 0);
            }
        }
        __syncthreads();   // drains vmcnt(0): next buffer ready; reads of cur done
    }

    // bounce C (bias added) to col-major LDS bf16 (aliases staging bufs — safe after barrier)
    #pragma unroll
    for (int fm = 0; fm < 2; ++fm) {
        #pragma unroll
        for (int fn = 0; fn < 8; ++fn) {
            int col = fn * 16 + lr;
            int r0 = wrow + fm * 16 + lq * 4;
            short4v pk;
            #pragma unroll
            for (int j = 0; j < 4; ++j) pk[j] = (short)f2bf(acc[fm][fn][j] + bv[fn]);
            *(short4v*)&sm.Tr[col * 136 + r0] = pk;
        }
    }
    __syncthreads();

    // RoPE + transpose write: thread owns dim d for 32 rows
    int d = tid & 63;
    int grp = tid >> 6;
    int cq = 2 * d, ck = 2 * d + 1;
    int pq = (d < 32) ? (4 * d + 2) : (4 * (d - 32));
    int pk2 = pq + 1;
    float sgn = (d < 32) ? -1.0f : 1.0f;
    #pragma unroll
    for (int ch = 0; ch < 4; ++ch) {
        int r0 = grp * 32 + ch * 8;
        bf16x8 xq = *(const bf16x8*)&sm.Tr[cq * 136 + r0];
        bf16x8 xk = *(const bf16x8*)&sm.Tr[ck * 136 + r0];
        bf16x8 yq = *(const bf16x8*)&sm.Tr[pq * 136 + r0];
        bf16x8 yk = *(const bf16x8*)&sm.Tr[pk2 * 136 + r0];
        #pragma unroll
        for (int rr = 0; rr < 8; ++rr) {
            int gm = m0 + r0 + rr;
            int s  = gm & (S_LEN - 1);
            int bb = gm >> 10;
            float cv = cosT[s * 64 + d];
            float sv = sinT[s * 64 + d];
            float qv = (float)xq[rr] * cv + sgn * (float)yq[rr] * sv;
            float kv = (float)xk[rr] * cv + sgn * (float)yk[rr] * sv;
            size_t ob = (((size_t)bb * T_SZ + t) * S_LEN + s) * 64 + d;
            qout[ob] = f2bf(qv);
            kout[ob] = f2bf(kv);
        }
    }
}

// ---------------- kernel 3: logits compute tiles only (ti<=tj) ----------------
__global__ __launch_bounds__(256) void k_logits(
    const unsigned short* __restrict__ q,
    const unsigned short* __restrict__ k,
    const int* __restrict__ mask,
    float* __restrict__ out)
{
    __shared__ __align__(16) unsigned short As[128 * 64];
    __shared__ __align__(16) unsigned short Bs[128 * 64];
    __shared__ int mi[128], mj[128];

    int tid = threadIdx.x;
    int c = blockIdx.x;
    int bt = c / 36, r = c % 36;
    int ti = 0; while (r >= 8 - ti) { r -= 8 - ti; ++ti; }
    int tj = ti + r;
    size_t obase = ((size_t)bt * S_LEN + (size_t)ti * 128) * S_LEN + tj * 128;

    int b = bt / T_SZ;
    if (tid < 128) mi[tid] = mask[b * S_LEN + ti * 128 + tid];
    else           mj[tid - 128] = mask[b * S_LEN + tj * 128 + (tid - 128)];

    const unsigned short* qsrc = q + ((size_t)bt * S_LEN + (size_t)ti * 128) * 64;
    const unsigned short* ksrc = k + ((size_t)bt * S_LEN + (size_t)tj * 128) * 64;

    int lane = tid & 63;
    int wave = tid >> 6;
    #pragma unroll
    for (int it = 0; it < 4; ++it) {
        int gsi = (wave * 4 + it) * 64 + lane;
        int rr = gsi >> 3;
        int sw = gsi & 7;
        int off = rr * 64 + ((sw ^ (rr & 7)) << 3);
        gload_lds16(qsrc + off, &As[(wave * 4 + it) * 512]);
        gload_lds16(ksrc + off, &Bs[(wave * 4 + it) * 512]);
    }
    __syncthreads();

    int lr = lane & 15;
    int lq = lane >> 4;
    int wrow = wave * 32;

    f32x4 acc[2][8];
    #pragma unroll
    for (int i = 0; i < 2; ++i)
        #pragma unroll
        for (int j = 0; j < 8; ++j) acc[i][j] = (f32x4){0.f, 0.f, 0.f, 0.f};

    // swapped operands: D = K.Q^T tile -> lane&15 = out ROW, reg idx = out COL
    #pragma unroll
    for (int kb = 0; kb < 2; ++kb) {
        bf16x8 qf[2];
        #pragma unroll
        for (int fi = 0; fi < 2; ++fi) {
            int rr = wrow + fi * 16 + lr;
            int seg = kb * 4 + lq;
            qf[fi] = *(const bf16x8*)&As[rr * 64 + ((seg ^ (rr & 7)) * 8)];
        }
        #pragma unroll
        for (int fn = 0; fn < 8; ++fn) {
            int rr = fn * 16 + lr;
            int seg = kb * 4 + lq;
            bf16x8 kf = *(const bf16x8*)&Bs[rr * 64 + ((seg ^ (rr & 7)) * 8)];
            acc[0][fn] = __builtin_amdgcn_mfma_f32_16x16x32_bf16(kf, qf[0], acc[0][fn], 0, 0, 0);
            acc[1][fn] = __builtin_amdgcn_mfma_f32_16x16x32_bf16(kf, qf[1], acc[1][fn], 0, 0, 0);
        }
    }

    #pragma unroll
    for (int fi = 0; fi < 2; ++fi) {
        int il = wrow + fi * 16 + lr;
        int gi = ti * 128 + il;
        bool mrow = mi[il] != 0;
        size_t rbase = obase + (size_t)il * S_LEN;
        #pragma unroll
        for (int fn = 0; fn < 8; ++fn) {
            int j0 = fn * 16 + lq * 4;
            int gj0 = tj * 128 + j0;
            float4v v;
            #pragma unroll
            for (int e = 0; e < 4; ++e) {
                bool ok = mrow && (mj[j0 + e] != 0) && (gi <= gj0 + e);
                v[e] = ok ? acc[fi][fn][e] : NEG_VAL;
            }
            *(float4v*)&out[rbase + j0] = v;
        }
    }
}

extern "C" void kernel_launch(void* const* d_in, const int* in_sizes, int n_in,
                              void* d_out, int out_size, void* d_ws, size_t ws_size,
                              hipStream_t stream) {
    const float* hidden = (const float*)d_in[0];
    const int*   mask   = (const int*)d_in[1];
    const float* W      = (const float*)d_in[2];
    const float* bias   = (const float*)d_in[3];
    float* out = (float*)d_out;
    int Bsz = in_sizes[0] / (S_LEN * HID);

    char* ws = (char*)d_ws;
    float* cosT = (float*)ws;
    float* sinT = (float*)(ws + (size_t)S_LEN * 64 * 4);
    unsigned short* hidB = (unsigned short*)(ws + 2ull * S_LEN * 64 * 4);
    size_t hidElems = (size_t)Bsz * S_LEN * HID;
    unsigned short* wB = hidB + hidElems;
    size_t wElems = (size_t)2 * T_SZ * 64 * HID;
    unsigned short* qb = wB + wElems;
    size_t qkElems = (size_t)Bsz * T_SZ * S_LEN * 64;
    unsigned short* kb = qb + qkElems;

    int n8h = (int)(hidElems / 8);
    int n8w = (int)(wElems / 8);
    int nPrep = (n8h + n8w + S_LEN * 64 + 255) / 256;
    int nproj = Bsz * 72;                       // 128-row tiles * 9 t-blocks
    int nfill = Bsz * T_SZ * 28;                // strictly-below-diagonal tiles
    int ncomp = Bsz * T_SZ * 36;                // ti<=tj tiles

    k_prep<<<dim3(nPrep), dim3(256), 0, stream>>>(hidden, W, hidB, wB, cosT, sinT, n8h, n8w);
    k_proj_fill<<<dim3(nproj + nfill), dim3(256), 0, stream>>>(hidB, wB, bias, cosT, sinT,
                                                               qb, kb, out, nproj);
    k_logits<<<dim3(ncomp), dim3(256), 0, stream>>>(qb, kb, mask, out);
}